// Round 7
// baseline (255.939 us; speedup 1.0000x reference)
//
#include <hip/hip_runtime.h>
#include <math.h>

#define NND 50000
#define NED 500000
#define FDIM 128
#define NREL 8
#define KTOT 1152            // 128 self + 8*128 relations
#define TPB 32               // targets per block (fused kernel)
#define ROWB 2304            // KTOT * 2 bytes per LDS A row

typedef __attribute__((ext_vector_type(8))) short short8;
typedef __attribute__((ext_vector_type(4))) float f32x4;

static __device__ __forceinline__ unsigned short f2bf(float f) {
    unsigned u = __float_as_uint(f);
    u += 0x7FFFu + ((u >> 16) & 1u);   // round-to-nearest-even
    return (unsigned short)(u >> 16);
}
static __device__ __forceinline__ float bf2f(unsigned short b) {
    return __uint_as_float((unsigned)b << 16);
}

// ---------------- K1: per-node attention dots + bf16(x) into xb ----------------
__global__ void node_dots_kernel(const float* __restrict__ x,
                                 const float* __restrict__ wa,
                                 float* __restrict__ a_src,
                                 float* __restrict__ a_tgt,
                                 unsigned short* __restrict__ xb) {
    int gid  = blockIdx.x * blockDim.x + threadIdx.x;
    int node = gid >> 6;          // one wave per node
    int lane = threadIdx.x & 63;
    if (node >= NND) return;
    float2 v = *(const float2*)(x + (size_t)node * FDIM + lane * 2);
    ushort2 vb = { f2bf(v.x), f2bf(v.y) };
    *(ushort2*)(xb + (size_t)node * FDIM + lane * 2) = vb;
    float s1 = v.x * wa[2 * lane]        + v.y * wa[2 * lane + 1];
    float s2 = v.x * wa[FDIM + 2 * lane] + v.y * wa[FDIM + 2 * lane + 1];
#pragma unroll
    for (int off = 32; off > 0; off >>= 1) {
        s1 += __shfl_xor(s1, off);
        s2 += __shfl_xor(s2, off);
    }
    if (lane == 0) { a_src[node] = s1; a_tgt[node] = s2; }
}

// ---------------- weight prep: Bt[o][k] bf16 ----------------
__global__ void prep_bt_kernel(const float* __restrict__ Ws,
                               const float* __restrict__ Wr,
                               unsigned short* __restrict__ Bt) {
    int idx = blockIdx.x * blockDim.x + threadIdx.x;
    if (idx >= FDIM * KTOT) return;
    int o = idx / KTOT;
    int k = idx - o * KTOT;
    float v;
    if (k < FDIM) v = Ws[o * FDIM + k];
    else {
        int r = (k - FDIM) >> 7;
        int i = (k - FDIM) & 127;
        v = Wr[((size_t)r * FDIM + o) * FDIM + i];
    }
    Bt[idx] = f2bf(v);
}

// ---------------- sort stage ----------------
__global__ void hist_kernel(const int* __restrict__ ei, int* __restrict__ counts) {
    int e = blockIdx.x * blockDim.x + threadIdx.x;
    if (e >= NED) return;
    atomicAdd(&counts[ei[NED + e]], 1);
}

__global__ void scan_pass1(const int* __restrict__ counts, int* __restrict__ offs,
                           int* __restrict__ bsum, int n) {
    __shared__ int buf[1024];
    int gid = blockIdx.x * 1024 + threadIdx.x;
    int v = (gid < n) ? counts[gid] : 0;
    buf[threadIdx.x] = v;
    __syncthreads();
    for (int d = 1; d < 1024; d <<= 1) {
        int t = (threadIdx.x >= (unsigned)d) ? buf[threadIdx.x - d] : 0;
        __syncthreads();
        buf[threadIdx.x] += t;
        __syncthreads();
    }
    if (gid < n) offs[gid] = buf[threadIdx.x] - v;
    if (threadIdx.x == 1023) bsum[blockIdx.x] = buf[1023];
}

__global__ void scan_pass2(int* __restrict__ bsum, int nb) {
    int lane = threadIdx.x;
    int v = (lane < nb) ? bsum[lane] : 0;
    int orig = v;
#pragma unroll
    for (int d = 1; d < 64; d <<= 1) {
        int t = __shfl_up(v, d);
        if (lane >= d) v += t;
    }
    if (lane < nb) bsum[lane] = v - orig;
}

__global__ void scan_pass3(int* __restrict__ offs, const int* __restrict__ bsum, int n) {
    int gid = blockIdx.x * 1024 + threadIdx.x;
    if (gid < n) offs[gid] += bsum[blockIdx.x];
}

// scatter: compute sigmoid ONCE per edge, store {a, (rel<<16)|src} as 8-byte entry
__global__ void scatter_kernel(const int* __restrict__ ei, const int* __restrict__ et,
                               const float* __restrict__ a_src, const float* __restrict__ a_tgt,
                               const float* __restrict__ ba,
                               int* __restrict__ offs,
                               unsigned long long* __restrict__ sorted2) {
    int e = blockIdx.x * blockDim.x + threadIdx.x;
    if (e >= NED) return;
    int src = ei[e];
    int tgt = ei[NED + e];
    int rel = et[e];
    float s = a_src[src] + a_tgt[tgt] + ba[0];
    float a = 1.0f / (1.0f + __expf(-s));
    int pos = atomicAdd(&offs[tgt], 1);
    unsigned long long pk = ((unsigned long long)__float_as_uint(a) << 32)
                          | (unsigned)((rel << 16) | src);
    sorted2[pos] = pk;
}

// ---------------- FUSED: segsum (4-deep batching) -> LDS A-tile -> MFMA GEMM ----------------
// Block = 512 threads (8 waves) = 32 targets. LDS A = 32 x 1152 bf16, chunk-XOR swizzled.
// Phase 1: wave w aggregates targets w*4..w*4+3 into registers, writes bf16 rows to LDS.
// Phase 2: wave w computes out[rh*16 .. +15][cq*32 .. +31], K=1152, B streamed from L2.
__global__ __launch_bounds__(512) void fused_kernel(
        const int* __restrict__ offs, const unsigned long long* __restrict__ sorted2,
        const unsigned short* __restrict__ xb,
        const unsigned short* __restrict__ Bt,
        const float* __restrict__ br,
        const float* __restrict__ bs,
        float* __restrict__ out) {
    __shared__ __align__(16) unsigned short A_lds[TPB * KTOT];  // 73,728 B
    __shared__ __align__(16) float asum_lds[TPB][NREL];         // 1,024 B
    int tid  = threadIdx.x;
    int wave = tid >> 6;
    int lane = tid & 63;
    int t0   = blockIdx.x * TPB;

    // ---------------- phase 1 ----------------
    const ushort2* xl = (const ushort2*)xb + lane;   // lane's 4B slot; row stride 64
    int lq = lane >> 2;           // chunk-in-slice 0..15
    int ib = (lane & 3) * 4;      // byte offset within 16B chunk

#define ACC(PK, W) {                                                    \
        float a  = __uint_as_float((unsigned)((PK) >> 32));             \
        int  rel = (int)(((PK) >> 16) & 0xF);                           \
        float vx = bf2f((W).x), vy = bf2f((W).y);                       \
        switch (rel) {                                                  \
            case 0: c0.x += a*vx; c0.y += a*vy; s0 += a; break;         \
            case 1: c1.x += a*vx; c1.y += a*vy; s1 += a; break;         \
            case 2: c2.x += a*vx; c2.y += a*vy; s2 += a; break;         \
            case 3: c3.x += a*vx; c3.y += a*vy; s3 += a; break;         \
            case 4: c4.x += a*vx; c4.y += a*vy; s4 += a; break;         \
            case 5: c5.x += a*vx; c5.y += a*vy; s5 += a; break;         \
            case 6: c6.x += a*vx; c6.y += a*vy; s6 += a; break;         \
            default: c7.x += a*vx; c7.y += a*vy; s7 += a; break;        \
        }                                                               \
    }

    for (int tl = 0; tl < 4; ++tl) {
        int trow = wave * 4 + tl;          // local A row 0..31
        int tgt  = t0 + trow;
        bool valid = (tgt < NND);
        float2 c0 = {0,0}, c1 = {0,0}, c2 = {0,0}, c3 = {0,0};
        float2 c4 = {0,0}, c5 = {0,0}, c6 = {0,0}, c7 = {0,0};
        float s0=0,s1=0,s2=0,s3=0,s4=0,s5=0,s6=0,s7=0;
        ushort2 xv = {0, 0};
        if (valid) {
            int start = (tgt == 0) ? 0 : offs[tgt - 1];
            int end   = offs[tgt];
            int k = start;
            for (; k + 4 <= end; k += 4) {
                unsigned long long pk0 = sorted2[k];
                unsigned long long pk1 = sorted2[k + 1];
                unsigned long long pk2 = sorted2[k + 2];
                unsigned long long pk3 = sorted2[k + 3];
                ushort2 w0 = xl[(size_t)(pk0 & 0xFFFF) * 64];
                ushort2 w1 = xl[(size_t)(pk1 & 0xFFFF) * 64];
                ushort2 w2 = xl[(size_t)(pk2 & 0xFFFF) * 64];
                ushort2 w3 = xl[(size_t)(pk3 & 0xFFFF) * 64];
                ACC(pk0, w0); ACC(pk1, w1); ACC(pk2, w2); ACC(pk3, w3);
            }
            for (; k < end; ++k) {
                unsigned long long pk = sorted2[k];
                ushort2 w = xl[(size_t)(pk & 0xFFFF) * 64];
                ACC(pk, w);
            }
            xv = xl[(size_t)tgt * 64];
        }
        // write row trow: x slice (chunks 0..15) + 8 rel slices (chunks 16+16r..),
        // chunk low-3 bits XOR'd with (trow&7); each lane writes its ushort2 (4B).
        char* rowp = (char*)A_lds + trow * ROWB;
        int rx = trow & 7;
#define WSLICE(CB, VAL) { int c = (CB) + lq; int p = (c & ~7) | ((c & 7) ^ rx); \
        *(ushort2*)(rowp + p * 16 + ib) = (VAL); }
        WSLICE(0, xv);
        ushort2 wv;
        wv.x = f2bf(c0.x); wv.y = f2bf(c0.y); WSLICE(16 + 0 * 16, wv);
        wv.x = f2bf(c1.x); wv.y = f2bf(c1.y); WSLICE(16 + 1 * 16, wv);
        wv.x = f2bf(c2.x); wv.y = f2bf(c2.y); WSLICE(16 + 2 * 16, wv);
        wv.x = f2bf(c3.x); wv.y = f2bf(c3.y); WSLICE(16 + 3 * 16, wv);
        wv.x = f2bf(c4.x); wv.y = f2bf(c4.y); WSLICE(16 + 4 * 16, wv);
        wv.x = f2bf(c5.x); wv.y = f2bf(c5.y); WSLICE(16 + 5 * 16, wv);
        wv.x = f2bf(c6.x); wv.y = f2bf(c6.y); WSLICE(16 + 6 * 16, wv);
        wv.x = f2bf(c7.x); wv.y = f2bf(c7.y); WSLICE(16 + 7 * 16, wv);
#undef WSLICE
        if (lane == 0) {
            float4 q0 = { s0, s1, s2, s3 };
            float4 q1 = { s4, s5, s6, s7 };
            *(float4*)&asum_lds[trow][0] = q0;
            *(float4*)&asum_lds[trow][4] = q1;
        }
    }
#undef ACC
    __syncthreads();

    // ---------------- phase 2 ----------------
    int l15 = lane & 15;
    int lhi = lane >> 4;
    int rh  = wave >> 2;          // 0..1: row half (16 targets)
    int cq  = wave & 3;           // 0..3: col quarter (32 outputs)
    int arow = rh * 16 + l15;
    const char* arp = (const char*)A_lds + arow * ROWB;
    int rx2 = arow & 7;

    f32x4 acc0 = (f32x4){0.f, 0.f, 0.f, 0.f};
    f32x4 acc1 = (f32x4){0.f, 0.f, 0.f, 0.f};
    const unsigned short* bb = Bt + (size_t)(cq * 32 + l15) * KTOT + lhi * 8;
#pragma unroll 4
    for (int kk = 0; kk < KTOT / 32; ++kk) {
        int c = kk * 4 + lhi;
        int p = (c & ~7) | ((c & 7) ^ rx2);
        short8 a = *(const short8*)(arp + p * 16);
        short8 b0 = *(const short8*)(bb + kk * 32);
        short8 b1 = *(const short8*)(bb + 16 * KTOT + kk * 32);
        acc0 = __builtin_amdgcn_mfma_f32_16x16x32_bf16(a, b0, acc0, 0, 0, 0);
        acc1 = __builtin_amdgcn_mfma_f32_16x16x32_bf16(a, b1, acc1, 0, 0, 0);
    }

    // epilogue: out[row][col] = acc + bs[col] + sum_r asum[row][r]*br[r][col]
#pragma unroll
    for (int nt = 0; nt < 2; ++nt) {
        int col = cq * 32 + nt * 16 + l15;
        float bsv = bs[col];
        float b0 = br[0 * FDIM + col], b1 = br[1 * FDIM + col];
        float b2 = br[2 * FDIM + col], b3 = br[3 * FDIM + col];
        float b4 = br[4 * FDIM + col], b5 = br[5 * FDIM + col];
        float b6 = br[6 * FDIM + col], b7 = br[7 * FDIM + col];
        f32x4 av = nt ? acc1 : acc0;
#pragma unroll
        for (int j = 0; j < 4; ++j) {
            int lrow = rh * 16 + lhi * 4 + j;
            int row  = t0 + lrow;
            if (row >= NND) continue;
            const float* as = asum_lds[lrow];
            float v = av[j] + bsv;
            v += as[0] * b0 + as[1] * b1 + as[2] * b2 + as[3] * b3;
            v += as[4] * b4 + as[5] * b5 + as[6] * b6 + as[7] * b7;
            out[(size_t)row * FDIM + col] = v;
        }
    }
}

extern "C" void kernel_launch(void* const* d_in, const int* in_sizes, int n_in,
                              void* d_out, int out_size, void* d_ws, size_t ws_size,
                              hipStream_t stream) {
    const float* x  = (const float*)d_in[0];
    const int*   ei = (const int*)d_in[1];
    const int*   et = (const int*)d_in[2];
    const float* Wr = (const float*)d_in[3];
    const float* br = (const float*)d_in[4];
    const float* Ws = (const float*)d_in[5];
    const float* bs = (const float*)d_in[6];
    const float* wa = (const float*)d_in[7];
    const float* ba = (const float*)d_in[8];
    float* out = (float*)d_out;
    float* ws  = (float*)d_ws;

    // workspace layout (float units; all offsets even -> 8B alignment for sorted2)
    const size_t btF = ((size_t)FDIM * KTOT) / 2;
    const size_t xbF = ((size_t)NND * FDIM) / 2;
    size_t o = 0;
    unsigned short* Bt = (unsigned short*)(ws + o); o += btF;
    unsigned short* xb = (unsigned short*)(ws + o); o += xbF;
    float* a_src = ws + o; o += NND;
    float* a_tgt = ws + o; o += NND;
    int*   counts = (int*)(ws + o); o += NND;
    int*   offs   = (int*)(ws + o); o += NND;
    int*   bsum   = (int*)(ws + o); o += 64;
    unsigned long long* sorted2 = (unsigned long long*)(ws + o); o += 2 * (size_t)NED;
    if (ws_size < o * sizeof(float)) return;

    dim3 blk(256);
    const int nblk1024 = (NND + 1023) / 1024;

    hipMemsetAsync(counts, 0, NND * sizeof(int), stream);

    node_dots_kernel<<<(NND + 3) / 4, blk, 0, stream>>>(x, wa, a_src, a_tgt, xb);
    prep_bt_kernel<<<(FDIM * KTOT + 255) / 256, blk, 0, stream>>>(Ws, Wr, Bt);
    hist_kernel<<<(NED + 255) / 256, blk, 0, stream>>>(ei, counts);
    scan_pass1<<<nblk1024, 1024, 0, stream>>>(counts, offs, bsum, NND);
    scan_pass2<<<1, 64, 0, stream>>>(bsum, nblk1024);
    scan_pass3<<<nblk1024, 1024, 0, stream>>>(offs, bsum, NND);
    scatter_kernel<<<(NED + 255) / 256, blk, 0, stream>>>(ei, et, a_src, a_tgt, ba, offs, sorted2);
    fused_kernel<<<(NND + TPB - 1) / TPB, 512, 0, stream>>>(
        offs, sorted2, xb, Bt, br, bs, out);
}

// Round 8
// 157.616 us; speedup vs baseline: 1.6238x; 1.6238x over previous
//
#include <hip/hip_runtime.h>
#include <math.h>

#define NND 50000
#define NED 500000
#define FDIM 128
#define NREL 8
#define KTOT 1152            // 128 self + 8*128 relations
#define MPAD 50048           // NND rounded to 64
#define NEDP 650000          // padded edge capacity: NED + 3*NND

typedef __attribute__((ext_vector_type(8))) short short8;
typedef __attribute__((ext_vector_type(4))) float f32x4;
typedef const void __attribute__((address_space(1)))* gptr_t;
typedef void __attribute__((address_space(3)))* lptr_t;

static __device__ __forceinline__ unsigned short f2bf(float f) {
    unsigned u = __float_as_uint(f);
    u += 0x7FFFu + ((u >> 16) & 1u);   // round-to-nearest-even
    return (unsigned short)(u >> 16);
}
static __device__ __forceinline__ float bf2f(unsigned short b) {
    return __uint_as_float((unsigned)b << 16);
}

// ---------------- K1 (fused prep): node dots + bf16 copies + Bt prep + zeroing ----------------
// blocks [0,12500): 4 nodes/block (one wave per node): a_src/a_tgt dots, bf16(x) -> Abig & xb
// blocks [12500,12572): Bt prep, 8 elems/thread
// blocks [12572,12768): zero counts
// blocks [12768,12795): zero Abig pad rows (rows NND..MPAD-1)
#define NDB   12500
#define PBB   72
#define CZB   196
#define AZB   27
__global__ void node_dots_kernel(const float* __restrict__ x,
                                 const float* __restrict__ wa,
                                 float* __restrict__ a_src,
                                 float* __restrict__ a_tgt,
                                 unsigned short* __restrict__ Abig,
                                 unsigned short* __restrict__ xb,
                                 const float* __restrict__ Ws,
                                 const float* __restrict__ Wr,
                                 unsigned short* __restrict__ Bt,
                                 int* __restrict__ counts) {
    int b = blockIdx.x;
    if (b < NDB) {
        int gid  = b * 256 + threadIdx.x;
        int node = gid >> 6;          // one wave per node; 12500*4 = 50000 exact
        int lane = threadIdx.x & 63;
        float2 v = *(const float2*)(x + (size_t)node * FDIM + lane * 2);
        ushort2 vb = { f2bf(v.x), f2bf(v.y) };
        *(ushort2*)(Abig + (size_t)node * KTOT + lane * 2) = vb;
        *(ushort2*)(xb   + (size_t)node * FDIM + lane * 2) = vb;
        float s1 = v.x * wa[2 * lane]        + v.y * wa[2 * lane + 1];
        float s2 = v.x * wa[FDIM + 2 * lane] + v.y * wa[FDIM + 2 * lane + 1];
#pragma unroll
        for (int off = 32; off > 0; off >>= 1) {
            s1 += __shfl_xor(s1, off);
            s2 += __shfl_xor(s2, off);
        }
        if (lane == 0) { a_src[node] = s1; a_tgt[node] = s2; }
    } else if (b < NDB + PBB) {
        int idx0 = (b - NDB) * 2048 + threadIdx.x * 8;   // 72*2048 = 147456 = FDIM*KTOT
        int o  = idx0 / KTOT;
        int k0 = idx0 - o * KTOT;
        unsigned short tmp[8];
#pragma unroll
        for (int j = 0; j < 8; ++j) {
            int k = k0 + j;                               // stays within row (8 | KTOT)
            float v;
            if (k < FDIM) v = Ws[o * FDIM + k];
            else {
                int r = (k - FDIM) >> 7;
                int i = (k - FDIM) & 127;
                v = Wr[((size_t)r * FDIM + o) * FDIM + i];
            }
            tmp[j] = f2bf(v);
        }
        *(short8*)(Bt + idx0) = *(short8*)tmp;
    } else if (b < NDB + PBB + CZB) {
        int i = (b - NDB - PBB) * 256 + threadIdx.x;
        if (i < NND) counts[i] = 0;
    } else {
        int i = (b - NDB - PBB - CZB) * 256 + threadIdx.x;  // 27*256 = 6912 float4s exact
        float4 z = make_float4(0.f, 0.f, 0.f, 0.f);
        ((float4*)(Abig + (size_t)NND * KTOT))[i] = z;
    }
}

// ---------------- sort stage ----------------
__global__ void hist_kernel(const int* __restrict__ ei, int* __restrict__ counts) {
    int e = blockIdx.x * blockDim.x + threadIdx.x;
    if (e >= NED) return;
    atomicAdd(&counts[ei[NED + e]], 1);
}

// exclusive scan of PADDED counts ((c+3)&~3)
__global__ void scan_pass1(const int* __restrict__ counts, int* __restrict__ offs,
                           int* __restrict__ bsum, int n) {
    __shared__ int buf[1024];
    int gid = blockIdx.x * 1024 + threadIdx.x;
    int v = (gid < n) ? ((counts[gid] + 3) & ~3) : 0;
    buf[threadIdx.x] = v;
    __syncthreads();
    for (int d = 1; d < 1024; d <<= 1) {
        int t = (threadIdx.x >= (unsigned)d) ? buf[threadIdx.x - d] : 0;
        __syncthreads();
        buf[threadIdx.x] += t;
        __syncthreads();
    }
    if (gid < n) offs[gid] = buf[threadIdx.x] - v;
    if (threadIdx.x == 1023) bsum[blockIdx.x] = buf[1023];
}

__global__ void scan_pass2(int* __restrict__ bsum, int nb) {
    int lane = threadIdx.x;
    int v = (lane < nb) ? bsum[lane] : 0;
    int orig = v;
#pragma unroll
    for (int d = 1; d < 64; d <<= 1) {
        int t = __shfl_up(v, d);
        if (lane >= d) v += t;
    }
    if (lane < nb) bsum[lane] = v - orig;
}

// finalize padded starts; mirror into cur (scatter cursors); write total at offs[n]
__global__ void scan_pass3(int* __restrict__ offs, const int* __restrict__ bsum,
                           const int* __restrict__ counts, int* __restrict__ cur, int n) {
    int gid = blockIdx.x * 1024 + threadIdx.x;
    if (gid < n) {
        int v = offs[gid] + bsum[blockIdx.x];
        offs[gid] = v;
        cur[gid]  = v;
        if (gid == n - 1) offs[n] = v + ((counts[gid] + 3) & ~3);
    }
}

// scatter: compute sigmoid ONCE per edge, store {a, (rel<<16)|src} as 8-byte entry.
// Pad slots stay all-zero (memset) -> a=+0.0, src=0, rel=0: contributes exactly 0.
__global__ void scatter_kernel(const int* __restrict__ ei, const int* __restrict__ et,
                               const float* __restrict__ a_src, const float* __restrict__ a_tgt,
                               const float* __restrict__ ba,
                               int* __restrict__ cur,
                               unsigned long long* __restrict__ sorted2) {
    int e = blockIdx.x * blockDim.x + threadIdx.x;
    if (e >= NED) return;
    int src = ei[e];
    int tgt = ei[NED + e];
    int rel = et[e];
    float s = a_src[src] + a_tgt[tgt] + ba[0];
    float a = 1.0f / (1.0f + __expf(-s));
    int pos = atomicAdd(&cur[tgt], 1);
    unsigned long long pk = ((unsigned long long)__float_as_uint(a) << 32)
                          | (unsigned)((rel << 16) | src);
    sorted2[pos] = pk;
}

// ---------------- K2: gather segmented reduction, tail-free 4-deep batching ----------------
__global__ __launch_bounds__(256) void segsum_kernel(
        const int* __restrict__ offs, const unsigned long long* __restrict__ sorted2,
        const unsigned short* __restrict__ xb,
        unsigned short* __restrict__ Abig, float* __restrict__ asum) {
    int wid  = (blockIdx.x * blockDim.x + threadIdx.x) >> 6;
    int lane = threadIdx.x & 63;
    if (wid >= NND) return;
    int tgt   = wid;
    int start = offs[tgt];
    int end   = offs[tgt + 1];          // padded: (end-start) % 4 == 0

    float2 c0 = {0,0}, c1 = {0,0}, c2 = {0,0}, c3 = {0,0};
    float2 c4 = {0,0}, c5 = {0,0}, c6 = {0,0}, c7 = {0,0};
    float s0=0,s1=0,s2=0,s3=0,s4=0,s5=0,s6=0,s7=0;

    const ushort2* xl = (const ushort2*)xb + lane;   // lane's 4B slot; row stride 64

#define ACC(PK, W) {                                                    \
        float a  = __uint_as_float((unsigned)((PK) >> 32));             \
        int  rel = (int)(((PK) >> 16) & 0xF);                           \
        float vx = bf2f((W).x), vy = bf2f((W).y);                       \
        switch (rel) {                                                  \
            case 0: c0.x += a*vx; c0.y += a*vy; s0 += a; break;         \
            case 1: c1.x += a*vx; c1.y += a*vy; s1 += a; break;         \
            case 2: c2.x += a*vx; c2.y += a*vy; s2 += a; break;         \
            case 3: c3.x += a*vx; c3.y += a*vy; s3 += a; break;         \
            case 4: c4.x += a*vx; c4.y += a*vy; s4 += a; break;         \
            case 5: c5.x += a*vx; c5.y += a*vy; s5 += a; break;         \
            case 6: c6.x += a*vx; c6.y += a*vy; s6 += a; break;         \
            default: c7.x += a*vx; c7.y += a*vy; s7 += a; break;        \
        }                                                               \
    }

    for (int k = start; k < end; k += 4) {
        unsigned long long pk0 = sorted2[k];
        unsigned long long pk1 = sorted2[k + 1];
        unsigned long long pk2 = sorted2[k + 2];
        unsigned long long pk3 = sorted2[k + 3];
        ushort2 w0 = xl[(size_t)(pk0 & 0xFFFF) * 64];
        ushort2 w1 = xl[(size_t)(pk1 & 0xFFFF) * 64];
        ushort2 w2 = xl[(size_t)(pk2 & 0xFFFF) * 64];
        ushort2 w3 = xl[(size_t)(pk3 & 0xFFFF) * 64];
        ACC(pk0, w0); ACC(pk1, w1); ACC(pk2, w2); ACC(pk3, w3);
    }
#undef ACC

    unsigned short* base = Abig + (size_t)tgt * KTOT + FDIM + lane * 2;
    ushort2 w;
    w.x = f2bf(c0.x); w.y = f2bf(c0.y); *(ushort2*)(base + 0 * FDIM) = w;
    w.x = f2bf(c1.x); w.y = f2bf(c1.y); *(ushort2*)(base + 1 * FDIM) = w;
    w.x = f2bf(c2.x); w.y = f2bf(c2.y); *(ushort2*)(base + 2 * FDIM) = w;
    w.x = f2bf(c3.x); w.y = f2bf(c3.y); *(ushort2*)(base + 3 * FDIM) = w;
    w.x = f2bf(c4.x); w.y = f2bf(c4.y); *(ushort2*)(base + 4 * FDIM) = w;
    w.x = f2bf(c5.x); w.y = f2bf(c5.y); *(ushort2*)(base + 5 * FDIM) = w;
    w.x = f2bf(c6.x); w.y = f2bf(c6.y); *(ushort2*)(base + 6 * FDIM) = w;
    w.x = f2bf(c7.x); w.y = f2bf(c7.y); *(ushort2*)(base + 7 * FDIM) = w;
    if (lane == 0) {
        float* ab = asum + (size_t)tgt * NREL;
        ab[0]=s0; ab[1]=s1; ab[2]=s2; ab[3]=s3; ab[4]=s4; ab[5]=s5; ab[6]=s6; ab[7]=s7;
    }
}

// ---------------- K3: bf16 MFMA GEMM (r5-verified 64x128 tile) ----------------
__global__ __launch_bounds__(256) void mfma_gemm_kernel(
        const unsigned short* __restrict__ Abig,
        const unsigned short* __restrict__ Bt,
        const float* __restrict__ asum,
        const float* __restrict__ br,
        const float* __restrict__ bs,
        float* __restrict__ out) {
    __shared__ __align__(16) unsigned short AsB[64 * 64];    // 8 KB
    __shared__ __align__(16) unsigned short BsB[128 * 64];   // 16 KB
    int tid  = threadIdx.x;
    int wave = tid >> 6;
    int lane = tid & 63;
    int l15  = lane & 15;
    int lhi  = lane >> 4;
    int brow = blockIdx.x * 64;
    int wr = wave >> 1;          // 0..1
    int wc = wave & 1;           // 0..1

    f32x4 acc[2][4];
#pragma unroll
    for (int mi = 0; mi < 2; ++mi)
#pragma unroll
        for (int ni = 0; ni < 4; ++ni) acc[mi][ni] = (f32x4){0.f, 0.f, 0.f, 0.f};

    for (int kc = 0; kc < KTOT / 64; ++kc) {
#pragma unroll
        for (int q = 0; q < 2; ++q) {
            int c    = tid + q * 256;
            int trow = c >> 3;
            int csw  = (c & 7) ^ (trow & 7);
            const unsigned short* src = Abig + (size_t)(brow + trow) * KTOT + kc * 64 + csw * 8;
            __builtin_amdgcn_global_load_lds((gptr_t)src,
                (lptr_t)&AsB[wave * 512 + q * 2048], 16, 0, 0);
        }
#pragma unroll
        for (int q = 0; q < 4; ++q) {
            int c   = tid + q * 256;
            int o   = c >> 3;
            int csw = (c & 7) ^ (o & 7);
            const unsigned short* src = Bt + (size_t)o * KTOT + kc * 64 + csw * 8;
            __builtin_amdgcn_global_load_lds((gptr_t)src,
                (lptr_t)&BsB[wave * 512 + q * 2048], 16, 0, 0);
        }
        __syncthreads();
#pragma unroll
        for (int ks = 0; ks < 2; ++ks) {
            int kslot = ks * 4 + lhi;
            short8 a[2], b[4];
#pragma unroll
            for (int mi = 0; mi < 2; ++mi) {
                int row = wr * 32 + mi * 16 + l15;
                a[mi] = *(const short8*)&AsB[row * 64 + ((kslot ^ (row & 7)) << 3)];
            }
#pragma unroll
            for (int ni = 0; ni < 4; ++ni) {
                int o = wc * 64 + ni * 16 + l15;
                b[ni] = *(const short8*)&BsB[o * 64 + ((kslot ^ (o & 7)) << 3)];
            }
#pragma unroll
            for (int mi = 0; mi < 2; ++mi)
#pragma unroll
                for (int ni = 0; ni < 4; ++ni)
                    acc[mi][ni] = __builtin_amdgcn_mfma_f32_16x16x32_bf16(
                        a[mi], b[ni], acc[mi][ni], 0, 0, 0);
        }
        __syncthreads();
    }

#pragma unroll
    for (int mi = 0; mi < 2; ++mi) {
        int rowbase = brow + wr * 32 + mi * 16 + lhi * 4;
#pragma unroll
        for (int j = 0; j < 4; ++j) {
            int row = rowbase + j;
            if (row >= NND) continue;
            const float* as = asum + (size_t)row * NREL;
            float4 sa = *(const float4*)as;
            float4 sb = *(const float4*)(as + 4);
#pragma unroll
            for (int ni = 0; ni < 4; ++ni) {
                int col = wc * 64 + ni * 16 + l15;
                float v = acc[mi][ni][j] + bs[col];
                v += sa.x * br[0 * FDIM + col] + sa.y * br[1 * FDIM + col]
                   + sa.z * br[2 * FDIM + col] + sa.w * br[3 * FDIM + col];
                v += sb.x * br[4 * FDIM + col] + sb.y * br[5 * FDIM + col]
                   + sb.z * br[6 * FDIM + col] + sb.w * br[7 * FDIM + col];
                out[(size_t)row * FDIM + col] = v;
            }
        }
    }
}

extern "C" void kernel_launch(void* const* d_in, const int* in_sizes, int n_in,
                              void* d_out, int out_size, void* d_ws, size_t ws_size,
                              hipStream_t stream) {
    const float* x  = (const float*)d_in[0];
    const int*   ei = (const int*)d_in[1];
    const int*   et = (const int*)d_in[2];
    const float* Wr = (const float*)d_in[3];
    const float* br = (const float*)d_in[4];
    const float* Ws = (const float*)d_in[5];
    const float* bs = (const float*)d_in[6];
    const float* wa = (const float*)d_in[7];
    const float* ba = (const float*)d_in[8];
    float* out = (float*)d_out;
    float* ws  = (float*)d_ws;

    // workspace layout (float units; even offsets keep 8B alignment for sorted2)
    const size_t abigF = ((size_t)MPAD * KTOT) / 2;
    const size_t btF   = ((size_t)FDIM * KTOT) / 2;
    const size_t xbF   = ((size_t)NND * FDIM) / 2;
    size_t o = 0;
    unsigned short* Abig = (unsigned short*)(ws + o); o += abigF;
    unsigned short* Bt   = (unsigned short*)(ws + o); o += btF;
    unsigned short* xb   = (unsigned short*)(ws + o); o += xbF;
    float* asum  = ws + o; o += (size_t)NND * NREL;
    float* a_src = ws + o; o += NND;
    float* a_tgt = ws + o; o += NND;
    int*   counts = (int*)(ws + o); o += NND;
    int*   offs   = (int*)(ws + o); o += NND + 2;   // NND+1 used, +1 pad for evenness
    int*   cur    = (int*)(ws + o); o += NND;
    int*   bsum   = (int*)(ws + o); o += 64;
    unsigned long long* sorted2 = (unsigned long long*)(ws + o); o += 2 * (size_t)NEDP;
    if (ws_size < o * sizeof(float)) return;

    dim3 blk(256);
    const int nblk1024 = (NND + 1023) / 1024;

    hipMemsetAsync(sorted2, 0, (size_t)NEDP * 8, stream);
    node_dots_kernel<<<NDB + PBB + CZB + AZB, blk, 0, stream>>>(
        x, wa, a_src, a_tgt, Abig, xb, Ws, Wr, Bt, counts);
    hist_kernel<<<(NED + 255) / 256, blk, 0, stream>>>(ei, counts);
    scan_pass1<<<nblk1024, 1024, 0, stream>>>(counts, offs, bsum, NND);
    scan_pass2<<<1, 64, 0, stream>>>(bsum, nblk1024);
    scan_pass3<<<nblk1024, 1024, 0, stream>>>(offs, bsum, counts, cur, NND);
    scatter_kernel<<<(NED + 255) / 256, blk, 0, stream>>>(ei, et, a_src, a_tgt, ba, cur, sorted2);
    segsum_kernel<<<(NND + 3) / 4, blk, 0, stream>>>(offs, sorted2, xb, Abig, asum);
    mfma_gemm_kernel<<<MPAD / 64, blk, 0, stream>>>(Abig, Bt, asum, br, bs, out);
}

// Round 9
// 155.743 us; speedup vs baseline: 1.6433x; 1.0120x over previous
//
#include <hip/hip_runtime.h>
#include <math.h>

#define NND 50000
#define NED 500000
#define FDIM 128
#define NREL 8
#define KTOT 1152            // 128 self + 8*128 relations
#define MPAD 50048           // NND rounded to 64
#define NEDP 650000          // padded edge capacity: NED + 3*NND
#define NKC  (KTOT / 64)     // 18 K-steps

typedef __attribute__((ext_vector_type(8))) short short8;
typedef __attribute__((ext_vector_type(4))) float f32x4;
typedef const void __attribute__((address_space(1)))* gptr_t;
typedef void __attribute__((address_space(3)))* lptr_t;

static __device__ __forceinline__ unsigned short f2bf(float f) {
    unsigned u = __float_as_uint(f);
    u += 0x7FFFu + ((u >> 16) & 1u);   // round-to-nearest-even
    return (unsigned short)(u >> 16);
}
static __device__ __forceinline__ float bf2f(unsigned short b) {
    return __uint_as_float((unsigned)b << 16);
}

// ---------------- K1 (fused prep): node dots + bf16 copies + Bt prep + zeroing ----------------
#define NDB   12500
#define PBB   72
#define CZB   196
#define AZB   27
__global__ void node_dots_kernel(const float* __restrict__ x,
                                 const float* __restrict__ wa,
                                 float* __restrict__ a_src,
                                 float* __restrict__ a_tgt,
                                 unsigned short* __restrict__ Abig,
                                 unsigned short* __restrict__ xb,
                                 const float* __restrict__ Ws,
                                 const float* __restrict__ Wr,
                                 unsigned short* __restrict__ Bt,
                                 int* __restrict__ counts) {
    int b = blockIdx.x;
    if (b < NDB) {
        int gid  = b * 256 + threadIdx.x;
        int node = gid >> 6;          // one wave per node; 12500*4 = 50000 exact
        int lane = threadIdx.x & 63;
        float2 v = *(const float2*)(x + (size_t)node * FDIM + lane * 2);
        ushort2 vb = { f2bf(v.x), f2bf(v.y) };
        *(ushort2*)(Abig + (size_t)node * KTOT + lane * 2) = vb;
        *(ushort2*)(xb   + (size_t)node * FDIM + lane * 2) = vb;
        float s1 = v.x * wa[2 * lane]        + v.y * wa[2 * lane + 1];
        float s2 = v.x * wa[FDIM + 2 * lane] + v.y * wa[FDIM + 2 * lane + 1];
#pragma unroll
        for (int off = 32; off > 0; off >>= 1) {
            s1 += __shfl_xor(s1, off);
            s2 += __shfl_xor(s2, off);
        }
        if (lane == 0) { a_src[node] = s1; a_tgt[node] = s2; }
    } else if (b < NDB + PBB) {
        int idx0 = (b - NDB) * 2048 + threadIdx.x * 8;   // 72*2048 = 147456 = FDIM*KTOT
        int o  = idx0 / KTOT;
        int k0 = idx0 - o * KTOT;
        unsigned short tmp[8];
#pragma unroll
        for (int j = 0; j < 8; ++j) {
            int k = k0 + j;
            float v;
            if (k < FDIM) v = Ws[o * FDIM + k];
            else {
                int r = (k - FDIM) >> 7;
                int i = (k - FDIM) & 127;
                v = Wr[((size_t)r * FDIM + o) * FDIM + i];
            }
            tmp[j] = f2bf(v);
        }
        *(short8*)(Bt + idx0) = *(short8*)tmp;
    } else if (b < NDB + PBB + CZB) {
        int i = (b - NDB - PBB) * 256 + threadIdx.x;
        if (i < NND) counts[i] = 0;
    } else {
        int i = (b - NDB - PBB - CZB) * 256 + threadIdx.x;  // 27*256 = 6912 float4s exact
        float4 z = make_float4(0.f, 0.f, 0.f, 0.f);
        ((float4*)(Abig + (size_t)NND * KTOT))[i] = z;
    }
}

// ---------------- sort stage ----------------
__global__ void hist_kernel(const int* __restrict__ ei, int* __restrict__ counts) {
    int e = blockIdx.x * blockDim.x + threadIdx.x;
    if (e >= NED) return;
    atomicAdd(&counts[ei[NED + e]], 1);
}

// exclusive scan of PADDED counts ((c+3)&~3)
__global__ void scan_pass1(const int* __restrict__ counts, int* __restrict__ offs,
                           int* __restrict__ bsum, int n) {
    __shared__ int buf[1024];
    int gid = blockIdx.x * 1024 + threadIdx.x;
    int v = (gid < n) ? ((counts[gid] + 3) & ~3) : 0;
    buf[threadIdx.x] = v;
    __syncthreads();
    for (int d = 1; d < 1024; d <<= 1) {
        int t = (threadIdx.x >= (unsigned)d) ? buf[threadIdx.x - d] : 0;
        __syncthreads();
        buf[threadIdx.x] += t;
        __syncthreads();
    }
    if (gid < n) offs[gid] = buf[threadIdx.x] - v;
    if (threadIdx.x == 1023) bsum[blockIdx.x] = buf[1023];
}

__global__ void scan_pass2(int* __restrict__ bsum, int nb) {
    int lane = threadIdx.x;
    int v = (lane < nb) ? bsum[lane] : 0;
    int orig = v;
#pragma unroll
    for (int d = 1; d < 64; d <<= 1) {
        int t = __shfl_up(v, d);
        if (lane >= d) v += t;
    }
    if (lane < nb) bsum[lane] = v - orig;
}

// finalize padded starts; mirror into cur; zero the <=3 pad slots per segment; total at offs[n]
__global__ void scan_pass3(int* __restrict__ offs, const int* __restrict__ bsum,
                           const int* __restrict__ counts, int* __restrict__ cur,
                           unsigned long long* __restrict__ sorted2, int n) {
    int gid = blockIdx.x * 1024 + threadIdx.x;
    if (gid < n) {
        int v = offs[gid] + bsum[blockIdx.x];
        offs[gid] = v;
        cur[gid]  = v;
        int c  = counts[gid];
        int cp = (c + 3) & ~3;
        for (int p = v + c; p < v + cp; ++p) sorted2[p] = 0ull;   // pad: a=+0, src=0, rel=0
        if (gid == n - 1) offs[n] = v + cp;
    }
}

// scatter: compute sigmoid ONCE per edge, store {a, (rel<<16)|src} as 8-byte entry.
__global__ void scatter_kernel(const int* __restrict__ ei, const int* __restrict__ et,
                               const float* __restrict__ a_src, const float* __restrict__ a_tgt,
                               const float* __restrict__ ba,
                               int* __restrict__ cur,
                               unsigned long long* __restrict__ sorted2) {
    int e = blockIdx.x * blockDim.x + threadIdx.x;
    if (e >= NED) return;
    int src = ei[e];
    int tgt = ei[NED + e];
    int rel = et[e];
    float s = a_src[src] + a_tgt[tgt] + ba[0];
    float a = 1.0f / (1.0f + __expf(-s));
    int pos = atomicAdd(&cur[tgt], 1);
    unsigned long long pk = ((unsigned long long)__float_as_uint(a) << 32)
                          | (unsigned)((rel << 16) | src);
    sorted2[pos] = pk;
}

// ---------------- K2: gather segmented reduction, tail-free 4-deep batching ----------------
__global__ __launch_bounds__(256) void segsum_kernel(
        const int* __restrict__ offs, const unsigned long long* __restrict__ sorted2,
        const unsigned short* __restrict__ xb,
        unsigned short* __restrict__ Abig, float* __restrict__ asum) {
    int wid  = (blockIdx.x * blockDim.x + threadIdx.x) >> 6;
    int lane = threadIdx.x & 63;
    if (wid >= NND) return;
    int tgt   = wid;
    int start = offs[tgt];
    int end   = offs[tgt + 1];          // padded: (end-start) % 4 == 0

    float2 c0 = {0,0}, c1 = {0,0}, c2 = {0,0}, c3 = {0,0};
    float2 c4 = {0,0}, c5 = {0,0}, c6 = {0,0}, c7 = {0,0};
    float s0=0,s1=0,s2=0,s3=0,s4=0,s5=0,s6=0,s7=0;

    const ushort2* xl = (const ushort2*)xb + lane;   // lane's 4B slot; row stride 64

#define ACC(PK, W) {                                                    \
        float a  = __uint_as_float((unsigned)((PK) >> 32));             \
        int  rel = (int)(((PK) >> 16) & 0xF);                           \
        float vx = bf2f((W).x), vy = bf2f((W).y);                       \
        switch (rel) {                                                  \
            case 0: c0.x += a*vx; c0.y += a*vy; s0 += a; break;         \
            case 1: c1.x += a*vx; c1.y += a*vy; s1 += a; break;         \
            case 2: c2.x += a*vx; c2.y += a*vy; s2 += a; break;         \
            case 3: c3.x += a*vx; c3.y += a*vy; s3 += a; break;         \
            case 4: c4.x += a*vx; c4.y += a*vy; s4 += a; break;         \
            case 5: c5.x += a*vx; c5.y += a*vy; s5 += a; break;         \
            case 6: c6.x += a*vx; c6.y += a*vy; s6 += a; break;         \
            default: c7.x += a*vx; c7.y += a*vy; s7 += a; break;        \
        }                                                               \
    }

    for (int k = start; k < end; k += 4) {
        unsigned long long pk0 = sorted2[k];
        unsigned long long pk1 = sorted2[k + 1];
        unsigned long long pk2 = sorted2[k + 2];
        unsigned long long pk3 = sorted2[k + 3];
        ushort2 w0 = xl[(size_t)(pk0 & 0xFFFF) * 64];
        ushort2 w1 = xl[(size_t)(pk1 & 0xFFFF) * 64];
        ushort2 w2 = xl[(size_t)(pk2 & 0xFFFF) * 64];
        ushort2 w3 = xl[(size_t)(pk3 & 0xFFFF) * 64];
        ACC(pk0, w0); ACC(pk1, w1); ACC(pk2, w2); ACC(pk3, w3);
    }
#undef ACC

    unsigned short* base = Abig + (size_t)tgt * KTOT + FDIM + lane * 2;
    ushort2 w;
    w.x = f2bf(c0.x); w.y = f2bf(c0.y); *(ushort2*)(base + 0 * FDIM) = w;
    w.x = f2bf(c1.x); w.y = f2bf(c1.y); *(ushort2*)(base + 1 * FDIM) = w;
    w.x = f2bf(c2.x); w.y = f2bf(c2.y); *(ushort2*)(base + 2 * FDIM) = w;
    w.x = f2bf(c3.x); w.y = f2bf(c3.y); *(ushort2*)(base + 3 * FDIM) = w;
    w.x = f2bf(c4.x); w.y = f2bf(c4.y); *(ushort2*)(base + 4 * FDIM) = w;
    w.x = f2bf(c5.x); w.y = f2bf(c5.y); *(ushort2*)(base + 5 * FDIM) = w;
    w.x = f2bf(c6.x); w.y = f2bf(c6.y); *(ushort2*)(base + 6 * FDIM) = w;
    w.x = f2bf(c7.x); w.y = f2bf(c7.y); *(ushort2*)(base + 7 * FDIM) = w;
    if (lane == 0) {
        float* ab = asum + (size_t)tgt * NREL;
        ab[0]=s0; ab[1]=s1; ab[2]=s2; ab[3]=s3; ab[4]=s4; ab[5]=s5; ab[6]=s6; ab[7]=s7;
    }
}

// ---------------- K3: bf16 MFMA GEMM, LDS double-buffer + counted vmcnt ----------------
__global__ __launch_bounds__(256) void mfma_gemm_kernel(
        const unsigned short* __restrict__ Abig,
        const unsigned short* __restrict__ Bt,
        const float* __restrict__ asum,
        const float* __restrict__ br,
        const float* __restrict__ bs,
        float* __restrict__ out) {
    __shared__ __align__(16) unsigned short AsB[2][64 * 64];    // 2 x 8 KB
    __shared__ __align__(16) unsigned short BsB[2][128 * 64];   // 2 x 16 KB
    int tid  = threadIdx.x;
    int wave = tid >> 6;
    int lane = tid & 63;
    int l15  = lane & 15;
    int lhi  = lane >> 4;
    int brow = blockIdx.x * 64;
    int wr = wave >> 1;          // 0..1
    int wc = wave & 1;           // 0..1

    f32x4 acc[2][4];
#pragma unroll
    for (int mi = 0; mi < 2; ++mi)
#pragma unroll
        for (int ni = 0; ni < 4; ++ni) acc[mi][ni] = (f32x4){0.f, 0.f, 0.f, 0.f};

    // per-thread staging addresses (kc-invariant parts)
    int cA   = tid;                       // A chunks: tid, tid+256
    int cB   = tid;                       // B chunks: tid + q*256
    // stage(buf, kc): 2 A-loads + 4 B-loads = 6 global_load_lds per wave
#define STAGE(D, KC) {                                                           \
        _Pragma("unroll")                                                        \
        for (int q = 0; q < 2; ++q) {                                            \
            int c    = cA + q * 256;                                             \
            int trow = c >> 3;                                                   \
            int csw  = (c & 7) ^ (trow & 7);                                     \
            const unsigned short* srcp =                                         \
                Abig + (size_t)(brow + trow) * KTOT + (KC) * 64 + csw * 8;       \
            __builtin_amdgcn_global_load_lds((gptr_t)srcp,                       \
                (lptr_t)&AsB[D][wave * 512 + q * 2048], 16, 0, 0);               \
        }                                                                        \
        _Pragma("unroll")                                                        \
        for (int q = 0; q < 4; ++q) {                                            \
            int c   = cB + q * 256;                                              \
            int o   = c >> 3;                                                    \
            int csw = (c & 7) ^ (o & 7);                                         \
            const unsigned short* srcp =                                         \
                Bt + (size_t)o * KTOT + (KC) * 64 + csw * 8;                     \
            __builtin_amdgcn_global_load_lds((gptr_t)srcp,                       \
                (lptr_t)&BsB[D][wave * 512 + q * 2048], 16, 0, 0);               \
        }                                                                        \
    }

    STAGE(0, 0);                          // prologue: 6 loads in flight
    for (int kc = 0; kc < NKC; ++kc) {
        int cur = kc & 1;
        if (kc + 1 < NKC) {
            STAGE(cur ^ 1, kc + 1);       // 12 in flight
            asm volatile("s_waitcnt vmcnt(6)" ::: "memory");   // retire this kc's 6
        } else {
            asm volatile("s_waitcnt vmcnt(0)" ::: "memory");
        }
        asm volatile("s_barrier" ::: "memory");   // all waves: buf[cur] ready
#pragma unroll
        for (int ks = 0; ks < 2; ++ks) {
            int kslot = ks * 4 + lhi;
            short8 a[2], b[4];
#pragma unroll
            for (int mi = 0; mi < 2; ++mi) {
                int row = wr * 32 + mi * 16 + l15;
                a[mi] = *(const short8*)&AsB[cur][row * 64 + ((kslot ^ (row & 7)) << 3)];
            }
#pragma unroll
            for (int ni = 0; ni < 4; ++ni) {
                int o = wc * 64 + ni * 16 + l15;
                b[ni] = *(const short8*)&BsB[cur][o * 64 + ((kslot ^ (o & 7)) << 3)];
            }
#pragma unroll
            for (int mi = 0; mi < 2; ++mi)
#pragma unroll
                for (int ni = 0; ni < 4; ++ni)
                    acc[mi][ni] = __builtin_amdgcn_mfma_f32_16x16x32_bf16(
                        a[mi], b[ni], acc[mi][ni], 0, 0, 0);
        }
        asm volatile("s_waitcnt lgkmcnt(0)" ::: "memory");   // ds_reads of buf[cur] retired
        asm volatile("s_barrier" ::: "memory");              // before next overwrite
    }
#undef STAGE

#pragma unroll
    for (int mi = 0; mi < 2; ++mi) {
        int rowbase = brow + wr * 32 + mi * 16 + lhi * 4;
#pragma unroll
        for (int j = 0; j < 4; ++j) {
            int row = rowbase + j;
            if (row >= NND) continue;
            const float* as = asum + (size_t)row * NREL;
            float4 sa = *(const float4*)as;
            float4 sb = *(const float4*)(as + 4);
#pragma unroll
            for (int ni = 0; ni < 4; ++ni) {
                int col = wc * 64 + ni * 16 + l15;
                float v = acc[mi][ni][j] + bs[col];
                v += sa.x * br[0 * FDIM + col] + sa.y * br[1 * FDIM + col]
                   + sa.z * br[2 * FDIM + col] + sa.w * br[3 * FDIM + col];
                v += sb.x * br[4 * FDIM + col] + sb.y * br[5 * FDIM + col]
                   + sb.z * br[6 * FDIM + col] + sb.w * br[7 * FDIM + col];
                out[(size_t)row * FDIM + col] = v;
            }
        }
    }
}

extern "C" void kernel_launch(void* const* d_in, const int* in_sizes, int n_in,
                              void* d_out, int out_size, void* d_ws, size_t ws_size,
                              hipStream_t stream) {
    const float* x  = (const float*)d_in[0];
    const int*   ei = (const int*)d_in[1];
    const int*   et = (const int*)d_in[2];
    const float* Wr = (const float*)d_in[3];
    const float* br = (const float*)d_in[4];
    const float* Ws = (const float*)d_in[5];
    const float* bs = (const float*)d_in[6];
    const float* wa = (const float*)d_in[7];
    const float* ba = (const float*)d_in[8];
    float* out = (float*)d_out;
    float* ws  = (float*)d_ws;

    // workspace layout (float units; even offsets keep 8B alignment for sorted2)
    const size_t abigF = ((size_t)MPAD * KTOT) / 2;
    const size_t btF   = ((size_t)FDIM * KTOT) / 2;
    const size_t xbF   = ((size_t)NND * FDIM) / 2;
    size_t o = 0;
    unsigned short* Abig = (unsigned short*)(ws + o); o += abigF;
    unsigned short* Bt   = (unsigned short*)(ws + o); o += btF;
    unsigned short* xb   = (unsigned short*)(ws + o); o += xbF;
    float* asum  = ws + o; o += (size_t)NND * NREL;
    float* a_src = ws + o; o += NND;
    float* a_tgt = ws + o; o += NND;
    int*   counts = (int*)(ws + o); o += NND;
    int*   offs   = (int*)(ws + o); o += NND + 2;
    int*   cur    = (int*)(ws + o); o += NND;
    int*   bsum   = (int*)(ws + o); o += 64;
    unsigned long long* sorted2 = (unsigned long long*)(ws + o); o += 2 * (size_t)NEDP;
    if (ws_size < o * sizeof(float)) return;

    dim3 blk(256);
    const int nblk1024 = (NND + 1023) / 1024;

    node_dots_kernel<<<NDB + PBB + CZB + AZB, blk, 0, stream>>>(
        x, wa, a_src, a_tgt, Abig, xb, Ws, Wr, Bt, counts);
    hist_kernel<<<(NED + 255) / 256, blk, 0, stream>>>(ei, counts);
    scan_pass1<<<nblk1024, 1024, 0, stream>>>(counts, offs, bsum, NND);
    scan_pass2<<<1, 64, 0, stream>>>(bsum, nblk1024);
    scan_pass3<<<nblk1024, 1024, 0, stream>>>(offs, bsum, counts, cur, sorted2, NND);
    scatter_kernel<<<(NED + 255) / 256, blk, 0, stream>>>(ei, et, a_src, a_tgt, ba, cur, sorted2);
    segsum_kernel<<<(NND + 3) / 4, blk, 0, stream>>>(offs, sorted2, xb, Abig, asum);
    mfma_gemm_kernel<<<MPAD / 64, blk, 0, stream>>>(Abig, Bt, asum, br, bs, out);
}